// Round 7
// baseline (234.643 us; speedup 1.0000x reference)
//
#include <hip/hip_runtime.h>

#define N_NODES 50000
#define DIM     128
#define N_EDGES 800000
#define N_LABEL 200000
#define SENT    N_NODES      // sentinel (zero) row index, fits in ushort

// column-blocked h tables: 4 parts, part p holds cols [32p, 32p+32) of all rows.
// per part: (N_NODES+1) rows x 64B
#define PBU ((N_NODES + 1) * 16)   // uints per part
#define PB4 ((N_NODES + 1) * 4)    // uint4 per part

// bucket partition: bucket = dst >> 5 (32 nodes/bucket), fixed capacity slots
#define NBUCK 1563           // ceil(50000/32)
#define CAP   1024           // slots per bucket (mean fill ~512, 22-sigma margin)
#define NPBLK 250            // partition blocks
#define CHUNK 3200           // edges per partition block

typedef __attribute__((ext_vector_type(8)))  short short8;    // 8 bf16 (4 VGPRs)
typedef __attribute__((ext_vector_type(16))) float floatx16;  // 32x32 MFMA acc

// split fp32 into bf16 hi + bf16 lo (x ~= hi + lo, rel err ~2^-17), RNE both
__device__ inline void f32_to_bf16x2(float x, unsigned short& hi, unsigned short& lo) {
    unsigned u  = __float_as_uint(x);
    unsigned rh = (u + 0x7FFFu + ((u >> 16) & 1u)) >> 16;
    hi = (unsigned short)rh;
    float hif = __uint_as_float(rh << 16);
    float r = x - hif;
    unsigned ul = __float_as_uint(r);
    unsigned rl = (ul + 0x7FFFu + ((ul >> 16) & 1u)) >> 16;
    lo = (unsigned short)rl;
}

__device__ inline unsigned short f32_to_bf16(float x) {
    unsigned u = __float_as_uint(x);
    return (unsigned short)((u + 0x7FFFu + ((u >> 16) & 1u)) >> 16);
}

__device__ inline unsigned pack_bf16x2(float a, float b) {
    return (unsigned)f32_to_bf16(a) | ((unsigned)f32_to_bf16(b) << 16);
}

__device__ inline float bf_lo(unsigned u) { return __uint_as_float(u << 16); }
__device__ inline float bf_hi(unsigned u) { return __uint_as_float(u & 0xFFFF0000u); }

// MERGED front-end (bcount pre-zeroed by hipMemsetAsync):
//  blocks [0, NPBLK): part_scatter chunks (launched first -> overlap with h0 build)
//  [NPBLK, NPBLK+6250): build hb0 (part-blocked bf16)
//  [NPBLK+6250, NPBLK+6282): swizzle W
//  NPBLK+6282: zero sentinel rows of hb0/hb1
__global__ __launch_bounds__(256)
void build_all(const int* __restrict__ n_id,
               const float* __restrict__ emb,
               const float* __restrict__ xs,
               unsigned* __restrict__ hb0, unsigned* __restrict__ hb1,
               const int* __restrict__ src, const int* __restrict__ dst,
               int* __restrict__ bcount, unsigned* __restrict__ part,
               const float* __restrict__ W1l, const float* __restrict__ W1r,
               const float* __restrict__ W2l, const float* __restrict__ W2r,
               unsigned short* __restrict__ WfH, unsigned short* __restrict__ WfL) {
    if (blockIdx.x < NPBLK) {
        // fused hist + range-reserve + grouped scatter for one edge chunk
        __shared__ int hist[NBUCK];      // pass1: counts; pass2: write cursors
        int t = threadIdx.x;
        for (int i = t; i < NBUCK; i += 256) hist[i] = 0;
        __syncthreads();
        int base = blockIdx.x * CHUNK;
        for (int e = base + t; e < base + CHUNK; e += 256)
            atomicAdd(&hist[dst[e] >> 5], 1);
        __syncthreads();
        for (int i = t; i < NBUCK; i += 256) {
            int c = hist[i];
            hist[i] = c ? atomicAdd(&bcount[i], c) : 0;   // reserve [base, base+c)
        }
        __syncthreads();
        for (int e = base + t; e < base + CHUNK; e += 256) {
            int d = dst[e];
            int bk = d >> 5;
            int pos = atomicAdd(&hist[bk], 1);
            part[bk * CAP + pos] = (unsigned)src[e] | ((unsigned)(d & 31) << 16);
        }
    } else if (blockIdx.x < NPBLK + 6250) {
        int t = (blockIdx.x - NPBLK) * 256 + threadIdx.x;   // < N_NODES*32 exactly
        int i = t >> 5, c = t & 31;                 // c covers cols 4c..4c+3
        float4 v;
        if (c < 16) {
            int nid = n_id[i];
            v = ((const float4*)emb)[nid * 16 + c];
        } else {
            v = ((const float4*)xs)[i * 16 + (c - 16)];
        }
        uint2 p;
        p.x = pack_bf16x2(v.x, v.y);
        p.y = pack_bf16x2(v.z, v.w);
        int pt = c >> 3;                            // 8 uint2-slots per part-row
        ((uint2*)hb0)[(size_t)pt * (PBU / 2) + (size_t)i * 8 + (c & 7)] = p;
    } else if (blockIdx.x < NPBLK + 6282) {
        int t = (blockIdx.x - NPBLK - 6250) * 256 + threadIdx.x;   // 8192 chunks
        if (t >= 8192) return;
        int L  = t & 63;
        int nt = (t >> 6) & 3;
        int ks = (t >> 8) & 7;
        int p  = (t >> 11) & 1;
        int ly = t >> 12;
        const float* Ws[4] = {W1l, W1r, W2l, W2r};
        const float* W = Ws[ly * 2 + p];
        int n = nt * 32 + (L & 31);
        int kbase = ks * 16 + (L >> 5) * 8;
        short8 hv, lv;
#pragma unroll
        for (int j = 0; j < 8; ++j) {
            unsigned short hh, ll;
            f32_to_bf16x2(W[(kbase + j) * DIM + n], hh, ll);
            hv[j] = (short)hh;
            lv[j] = (short)ll;
        }
        *(short8*)(WfH + (size_t)t * 8) = hv;
        *(short8*)(WfL + (size_t)t * 8) = lv;
    } else {
        // zero sentinel rows (row SENT) of all 4 parts of hb0 and hb1
        int u = threadIdx.x;
        if (u < 64) {
            int p = u >> 4;
            hb0[(size_t)p * PBU + (size_t)SENT * 16 + (u & 15)] = 0;
        } else if (u < 128) {
            int v = u - 64;
            int p = v >> 4;
            hb1[(size_t)p * PBU + (size_t)SENT * 16 + (v & 15)] = 0;
        }
    }
}

#define ACC8(A, v) { A[0]+=bf_lo((v).x); A[1]+=bf_hi((v).x); A[2]+=bf_lo((v).y); A[3]+=bf_hi((v).y); \
                     A[4]+=bf_lo((v).z); A[5]+=bf_hi((v).z); A[6]+=bf_lo((v).w); A[7]+=bf_hi((v).w); }

// FUSED csr-build + aggregate + linear, one 32-node tile (== csr bucket).
// CSRB=1 (layer 1): prologue builds localized csr in LDS from part[] (hist/scan/
//   scatter, the old bucket_csr dispatch) and persists lcsr + relative nbeg/nend
//   for layer 2. CSRB=0 (layer 2): stages the persisted csr.
// Gather: 4 column phases over part-blocked h (64B row-slices); csr indices read
//   from LDS (broadcast), 4 x 64B rows in flight per lane; shfl_xor(4,8) reduce.
// Phase B: 4 waves, wave w owns cols [32w, 32w+32) = output part w.
template <int RELU, int CSRB>
__global__ __launch_bounds__(256, 7)
void fused_sage(const unsigned* __restrict__ part, const int* __restrict__ bcount,
                int* __restrict__ nbeg, int* __restrict__ nend,
                unsigned short* __restrict__ csr,
                const unsigned* __restrict__ hsrc,
                const unsigned short* __restrict__ WfH,
                const unsigned short* __restrict__ WfL,
                const float* __restrict__ b,
                unsigned short* __restrict__ outb) {
    __shared__ uint4 aggtile[32][16];        // 8KB bf16 agg tile, swizzled slots
    __shared__ unsigned short lcsr[CAP];     // 2KB staged/built csr bucket
    __shared__ int lbe[32][2];               // per-node [beg,end) relative
    __shared__ int ldeg[32];
    __shared__ int lcur[32];
    int tid  = threadIdx.x;
    int lane = tid & 63;
    int g    = tid >> 4;                  // 16-lane group id (0..15)
    int c    = tid & 15;
    int bk   = blockIdx.x;
    int base = bk * CAP;
    int cnt  = bcount[bk];

    if (CSRB) {
        // ---- bucket_csr fused in: hist -> scan -> scatter (LDS-local) ----
        if (tid < 32) ldeg[tid] = 0;
        __syncthreads();
        for (int e = tid; e < cnt; e += 256)
            atomicAdd(&ldeg[part[base + e] >> 16], 1);
        __syncthreads();
        if (tid < 32) {                   // 32-wide scan in wave 0
            int v = ldeg[tid];
            int s = v;
#pragma unroll
            for (int off = 1; off < 32; off <<= 1) {
                int u = __shfl_up(s, off, 32);
                if (tid >= off) s += u;
            }
            int excl = s - v;
            lbe[tid][0] = excl;
            lbe[tid][1] = excl + v;
            lcur[tid]   = excl;
            int node = bk * 32 + tid;
            if (node < N_NODES) { nbeg[node] = excl; nend[node] = excl + v; }
        }
        __syncthreads();
        for (int e = tid; e < cnt; e += 256) {
            unsigned p = part[base + e];
            int pos = atomicAdd(&lcur[p >> 16], 1);
            lcsr[pos] = (unsigned short)(p & 0xFFFFu);
        }
        __syncthreads();
        // persist localized csr for layer 2 (fire-and-forget stores)
        for (int e = tid; e < cnt; e += 256) csr[base + e] = lcsr[e];
    } else {
        for (int e = tid; e < cnt; e += 256) lcsr[e] = csr[base + e];
        if (tid < 32) {
            int node = bk * 32 + tid;
            int b0 = 0, e0 = 0;
            if (node < N_NODES) { b0 = nbeg[node]; e0 = nend[node]; }
            lbe[tid][0] = b0; lbe[tid][1] = e0;
        }
        __syncthreads();
    }

    const uint4* H4 = (const uint4*)hsrc;
    int q   = c & 3;                      // uint4 col-slot within 64B row-slice
    int rsl = c >> 2;                     // row subslot 0..3

    // ---- phase A: 4 column phases (no inter-phase sync; slots disjoint) ----
    for (int p = 0; p < 4; ++p) {
        const uint4* Hp = H4 + (size_t)p * PB4;
#pragma unroll
        for (int nn = 0; nn < 2; ++nn) {
            int nl = g + nn * 16;
            int lb = lbe[nl][0], le = lbe[nl][1];
            float a[8] = {0.f,0.f,0.f,0.f,0.f,0.f,0.f,0.f};
            for (int pos = lb + rsl; pos < le; pos += 16) {
                int p1 = pos + 4, p2 = pos + 8, p3 = pos + 12;
                int r0 = (int)lcsr[pos];
                int r1 = (p1 < le) ? (int)lcsr[p1] : SENT;
                int r2 = (p2 < le) ? (int)lcsr[p2] : SENT;
                int r3 = (p3 < le) ? (int)lcsr[p3] : SENT;
                uint4 v0 = Hp[(size_t)r0 * 4 + q];
                uint4 v1 = Hp[(size_t)r1 * 4 + q];
                uint4 v2 = Hp[(size_t)r2 * 4 + q];
                uint4 v3 = Hp[(size_t)r3 * 4 + q];
                ACC8(a, v0); ACC8(a, v1); ACC8(a, v2); ACC8(a, v3);
            }
#pragma unroll
            for (int i = 0; i < 8; ++i) {
                a[i] += __shfl_xor(a[i], 4, 64);
                a[i] += __shfl_xor(a[i], 8, 64);
            }
            if (rsl == 0) {
                float rd = 1.0f / fmaxf((float)(le - lb), 1.0f);
                uint4 o;
                o.x = pack_bf16x2(a[0] * rd, a[1] * rd);
                o.y = pack_bf16x2(a[2] * rd, a[3] * rd);
                o.z = pack_bf16x2(a[4] * rd, a[5] * rd);
                o.w = pack_bf16x2(a[6] * rd, a[7] * rd);
                int s = p * 4 + q;                    // slot s <-> cols 8s..8s+7
                aggtile[nl][s ^ (nl & 7)] = o;
            }
        }
    }
    __syncthreads();

    // ---- phase B: MFMA, wave w owns cols [w*32, w*32+32) ----
    int w    = tid >> 6;                  // col-tile index == output part
    int ml   = lane & 31;                 // local row 0..31
    int mc   = min(bk * 32 + ml, N_NODES - 1);
    int kh   = lane >> 5;

    floatx16 acc;
#pragma unroll
    for (int i = 0; i < 16; ++i) acc[i] = 0.f;

    // agg term (A from LDS, slot kh+2*ks swizzled by row)
#pragma unroll
    for (int ks = 0; ks < 8; ++ks) {
        int slot = (kh + 2 * ks) ^ (ml & 7);
        short8 aa = *(const short8*)&aggtile[ml][slot];
        int cbase = (ks * 4 + w) * 64 + lane;
        short8 bh = *(const short8*)(WfH + (size_t)cbase * 8);
        short8 bl = *(const short8*)(WfL + (size_t)cbase * 8);
        acc = __builtin_amdgcn_mfma_f32_32x32x16_bf16(aa, bh, acc, 0, 0, 0);
        acc = __builtin_amdgcn_mfma_f32_32x32x16_bf16(aa, bl, acc, 0, 0, 0);
    }
    // self term (A from part-blocked global h rows)
#pragma unroll
    for (int ks = 0; ks < 8; ++ks) {
        int c8 = ks * 2 + kh;             // uint4 col-slot 0..15
        short8 aa = *(const short8*)&H4[(size_t)(c8 >> 2) * PB4 + (size_t)mc * 4 + (c8 & 3)];
        int cbase = ((8 + ks) * 4 + w) * 64 + lane;
        short8 bh = *(const short8*)(WfH + (size_t)cbase * 8);
        short8 bl = *(const short8*)(WfL + (size_t)cbase * 8);
        acc = __builtin_amdgcn_mfma_f32_32x32x16_bf16(aa, bh, acc, 0, 0, 0);
        acc = __builtin_amdgcn_mfma_f32_32x32x16_bf16(aa, bl, acc, 0, 0, 0);
    }

    int col0 = w * 32 + (lane & 31);
    float bb = b[col0];
    unsigned short* outp = outb + (size_t)w * (PBU * 2);   // part w, ushort units
#pragma unroll
    for (int reg = 0; reg < 16; ++reg) {
        int rloc = (reg & 3) + 8 * (reg >> 2) + 4 * kh;   // C/D row map (m74/m101)
        int rowg = bk * 32 + rloc;
        if (rowg < N_NODES) {
            float v0 = acc[reg] + bb;
            if (RELU) v0 = fmaxf(v0, 0.f);
            outp[(size_t)rowg * 32 + (lane & 31)] = f32_to_bf16(v0);
        }
    }
}

// logits from part-blocked bf16 h2; 8 lanes/edge, TWO edges per lane:
// 8 independent uint4 loads in flight per lane.
__global__ void edge_dot(const int* __restrict__ esrc, const int* __restrict__ edst,
                         const unsigned* __restrict__ h2b, float* __restrict__ out) {
    int t = blockIdx.x * blockDim.x + threadIdx.x;
    int e0 = t >> 3, c = t & 7;
    const int HALF = N_LABEL / 2;
    if (e0 >= HALF) return;
    int e1 = e0 + HALF;
    const uint4* H = (const uint4*)h2b;
    int p  = c >> 1;                       // part 0..3
    int q0 = (c & 1) * 2, q1 = q0 + 1;     // uint4 slots within part row
    size_t pb = (size_t)p * PB4;
    int rs0 = esrc[e0], rd0 = edst[e0];
    int rs1 = esrc[e1], rd1 = edst[e1];
    uint4 a0 = H[pb + (size_t)rs0 * 4 + q0];
    uint4 a1 = H[pb + (size_t)rs0 * 4 + q1];
    uint4 b0 = H[pb + (size_t)rd0 * 4 + q0];
    uint4 b1 = H[pb + (size_t)rd0 * 4 + q1];
    uint4 a2 = H[pb + (size_t)rs1 * 4 + q0];
    uint4 a3 = H[pb + (size_t)rs1 * 4 + q1];
    uint4 b2 = H[pb + (size_t)rd1 * 4 + q0];
    uint4 b3 = H[pb + (size_t)rd1 * 4 + q1];
    float p0 = bf_lo(a0.x) * bf_lo(b0.x) + bf_hi(a0.x) * bf_hi(b0.x)
             + bf_lo(a0.y) * bf_lo(b0.y) + bf_hi(a0.y) * bf_hi(b0.y)
             + bf_lo(a0.z) * bf_lo(b0.z) + bf_hi(a0.z) * bf_hi(b0.z)
             + bf_lo(a0.w) * bf_lo(b0.w) + bf_hi(a0.w) * bf_hi(b0.w)
             + bf_lo(a1.x) * bf_lo(b1.x) + bf_hi(a1.x) * bf_hi(b1.x)
             + bf_lo(a1.y) * bf_lo(b1.y) + bf_hi(a1.y) * bf_hi(b1.y)
             + bf_lo(a1.z) * bf_lo(b1.z) + bf_hi(a1.z) * bf_hi(b1.z)
             + bf_lo(a1.w) * bf_lo(b1.w) + bf_hi(a1.w) * bf_hi(b1.w);
    float p1 = bf_lo(a2.x) * bf_lo(b2.x) + bf_hi(a2.x) * bf_hi(b2.x)
             + bf_lo(a2.y) * bf_lo(b2.y) + bf_hi(a2.y) * bf_hi(b2.y)
             + bf_lo(a2.z) * bf_lo(b2.z) + bf_hi(a2.z) * bf_hi(b2.z)
             + bf_lo(a2.w) * bf_lo(b2.w) + bf_hi(a2.w) * bf_hi(b2.w)
             + bf_lo(a3.x) * bf_lo(b3.x) + bf_hi(a3.x) * bf_hi(b3.x)
             + bf_lo(a3.y) * bf_lo(b3.y) + bf_hi(a3.y) * bf_hi(b3.y)
             + bf_lo(a3.z) * bf_lo(b3.z) + bf_hi(a3.z) * bf_hi(b3.z)
             + bf_lo(a3.w) * bf_lo(b3.w) + bf_hi(a3.w) * bf_hi(b3.w);
#pragma unroll
    for (int off = 4; off; off >>= 1) {
        p0 += __shfl_down(p0, off, 8);
        p1 += __shfl_down(p1, off, 8);
    }
    if (c == 0) { out[e0] = p0; out[e1] = p1; }
}

extern "C" void kernel_launch(void* const* d_in, const int* in_sizes, int n_in,
                              void* d_out, int out_size, void* d_ws, size_t ws_size,
                              hipStream_t stream) {
    const int*   n_id     = (const int*)d_in[0];
    const float* x_struct = (const float*)d_in[1];
    const int*   e_idx    = (const int*)d_in[2];   // [2, N_EDGES]
    const int*   eli      = (const int*)d_in[3];   // [2, N_LABEL]
    const float* emb      = (const float*)d_in[4];
    const float* W1l      = (const float*)d_in[5];
    const float* W1r      = (const float*)d_in[6];
    const float* b1       = (const float*)d_in[7];
    const float* W2l      = (const float*)d_in[8];
    const float* W2r      = (const float*)d_in[9];
    const float* b2       = (const float*)d_in[10];
    float* out = (float*)d_out;

    const int* src = e_idx;
    const int* dst = e_idx + N_EDGES;

    const size_t ROWS = (size_t)4 * PBU;           // uints per table (4 parts)
    unsigned* hb2 = (unsigned*)d_ws;               // bf16 h2 (edge_dot input)
    unsigned* hb0 = hb2 + ROWS;                    // bf16 h0 (+sentinel)
    unsigned* hb1 = hb0 + ROWS;                    // bf16 h1 (+sentinel)
    int*   nbeg   = (int*)(hb1 + ROWS);            // relative [beg,end) per node
    int*   nend   = nbeg + N_NODES;
    int*   bcount = nend + N_NODES;                // NBUCK
    unsigned* part= (unsigned*)(bcount + NBUCK);   // NBUCK*CAP packed (src | local<<16)
    unsigned short* csr = (unsigned short*)(part + (size_t)NBUCK * CAP);  // NBUCK*CAP ushort
    uintptr_t wa  = ((uintptr_t)(csr + (size_t)NBUCK * CAP) + 15) & ~(uintptr_t)15;
    unsigned short* WfH = (unsigned short*)wa;     // 2*32768
    unsigned short* WfL = WfH + 2 * 32768;

    // bcount <- 0 (capture-safe async memset; 6KB)
    hipMemsetAsync(bcount, 0, NBUCK * sizeof(int), stream);

    // merged front-end: part_scatter (blocks 0..249, overlapped) + hb0 build +
    // W swizzle + sentinel zero
    build_all<<<NPBLK + 6283, 256, 0, stream>>>(
        n_id, emb, x_struct, hb0, hb1, src, dst, bcount, part,
        W1l, W1r, W2l, W2r, WfH, WfL);

    // layer 1: fused csr-build + aggregate + linear -> bf16 h1 (persists csr)
    fused_sage<1, 1><<<NBUCK, 256, 0, stream>>>(
        part, bcount, nbeg, nend, csr, hb0, WfH, WfL, b1, (unsigned short*)hb1);

    // layer 2: fused aggregate + linear -> bf16 h2
    fused_sage<0, 0><<<NBUCK, 256, 0, stream>>>(
        part, bcount, nbeg, nend, csr, hb1, WfH + 32768, WfL + 32768, b2,
        (unsigned short*)hb2);

    edge_dot<<<(N_LABEL / 2 * 8 + 255) / 256, 256, 0, stream>>>(eli, eli + N_LABEL, hb2, out);
}

// Round 8
// 204.229 us; speedup vs baseline: 1.1489x; 1.1489x over previous
//
#include <hip/hip_runtime.h>

#define N_NODES 50000
#define DIM     128
#define N_EDGES 800000
#define N_LABEL 200000
#define SENT    N_NODES      // sentinel (zero) row index, fits in ushort

// column-blocked h tables: 2 parts, part p holds cols [64p, 64p+64) of all rows.
// per part: (N_NODES+1) rows x 128B  -> gather granule = one 128B line
#define PPU ((N_NODES + 1) * 32)   // uints per part
#define PP4 ((N_NODES + 1) * 8)    // uint4 per part

// bucket partition: bucket = dst >> 5 (32 nodes/bucket), fixed capacity slots
#define NBUCK 1563           // ceil(50000/32)
#define CAP   1024           // slots per bucket (mean fill ~512, 22-sigma margin)
#define NPBLK 250            // partition blocks
#define CHUNK 3200           // edges per partition block

typedef __attribute__((ext_vector_type(8)))  short short8;    // 8 bf16 (4 VGPRs)
typedef __attribute__((ext_vector_type(16))) float floatx16;  // 32x32 MFMA acc

// split fp32 into bf16 hi + bf16 lo (x ~= hi + lo, rel err ~2^-17), RNE both
__device__ inline void f32_to_bf16x2(float x, unsigned short& hi, unsigned short& lo) {
    unsigned u  = __float_as_uint(x);
    unsigned rh = (u + 0x7FFFu + ((u >> 16) & 1u)) >> 16;
    hi = (unsigned short)rh;
    float hif = __uint_as_float(rh << 16);
    float r = x - hif;
    unsigned ul = __float_as_uint(r);
    unsigned rl = (ul + 0x7FFFu + ((ul >> 16) & 1u)) >> 16;
    lo = (unsigned short)rl;
}

__device__ inline unsigned short f32_to_bf16(float x) {
    unsigned u = __float_as_uint(x);
    return (unsigned short)((u + 0x7FFFu + ((u >> 16) & 1u)) >> 16);
}

__device__ inline unsigned pack_bf16x2(float a, float b) {
    return (unsigned)f32_to_bf16(a) | ((unsigned)f32_to_bf16(b) << 16);
}

__device__ inline float bf_lo(unsigned u) { return __uint_as_float(u << 16); }
__device__ inline float bf_hi(unsigned u) { return __uint_as_float(u & 0xFFFF0000u); }

// MERGED front-end (bcount pre-zeroed by hipMemsetAsync):
//  blocks [0, NPBLK): part_scatter chunks (launched first -> overlap with h0 build)
//  [NPBLK, NPBLK+6250): build hb0 (2-part-blocked bf16)
//  [NPBLK+6250, NPBLK+6282): swizzle W
//  NPBLK+6282: zero sentinel rows of hb0/hb1
__global__ __launch_bounds__(256)
void build_all(const int* __restrict__ n_id,
               const float* __restrict__ emb,
               const float* __restrict__ xs,
               unsigned* __restrict__ hb0, unsigned* __restrict__ hb1,
               const int* __restrict__ src, const int* __restrict__ dst,
               int* __restrict__ bcount, unsigned* __restrict__ part,
               const float* __restrict__ W1l, const float* __restrict__ W1r,
               const float* __restrict__ W2l, const float* __restrict__ W2r,
               unsigned short* __restrict__ WfH, unsigned short* __restrict__ WfL) {
    if (blockIdx.x < NPBLK) {
        // fused hist + range-reserve + grouped scatter for one edge chunk
        __shared__ int hist[NBUCK];      // pass1: counts; pass2: write cursors
        int t = threadIdx.x;
        for (int i = t; i < NBUCK; i += 256) hist[i] = 0;
        __syncthreads();
        int base = blockIdx.x * CHUNK;
        for (int e = base + t; e < base + CHUNK; e += 256)
            atomicAdd(&hist[dst[e] >> 5], 1);
        __syncthreads();
        for (int i = t; i < NBUCK; i += 256) {
            int c = hist[i];
            hist[i] = c ? atomicAdd(&bcount[i], c) : 0;   // reserve [base, base+c)
        }
        __syncthreads();
        for (int e = base + t; e < base + CHUNK; e += 256) {
            int d = dst[e];
            int bk = d >> 5;
            int pos = atomicAdd(&hist[bk], 1);
            part[bk * CAP + pos] = (unsigned)src[e] | ((unsigned)(d & 31) << 16);
        }
    } else if (blockIdx.x < NPBLK + 6250) {
        int t = (blockIdx.x - NPBLK) * 256 + threadIdx.x;   // < N_NODES*32 exactly
        int i = t >> 5, c = t & 31;                 // c covers cols 4c..4c+3
        float4 v;
        if (c < 16) {
            int nid = n_id[i];
            v = ((const float4*)emb)[nid * 16 + c];
        } else {
            v = ((const float4*)xs)[i * 16 + (c - 16)];
        }
        uint2 p;
        p.x = pack_bf16x2(v.x, v.y);
        p.y = pack_bf16x2(v.z, v.w);
        int pt = c >> 4;                            // part 0..1 (16 uint2 per part-row)
        ((uint2*)hb0)[(size_t)pt * (PPU / 2) + (size_t)i * 16 + (c & 15)] = p;
    } else if (blockIdx.x < NPBLK + 6282) {
        int t = (blockIdx.x - NPBLK - 6250) * 256 + threadIdx.x;   // 8192 chunks
        if (t >= 8192) return;
        int L  = t & 63;
        int nt = (t >> 6) & 3;
        int ks = (t >> 8) & 7;
        int p  = (t >> 11) & 1;
        int ly = t >> 12;
        const float* Ws[4] = {W1l, W1r, W2l, W2r};
        const float* W = Ws[ly * 2 + p];
        int n = nt * 32 + (L & 31);
        int kbase = ks * 16 + (L >> 5) * 8;
        short8 hv, lv;
#pragma unroll
        for (int j = 0; j < 8; ++j) {
            unsigned short hh, ll;
            f32_to_bf16x2(W[(kbase + j) * DIM + n], hh, ll);
            hv[j] = (short)hh;
            lv[j] = (short)ll;
        }
        *(short8*)(WfH + (size_t)t * 8) = hv;
        *(short8*)(WfL + (size_t)t * 8) = lv;
    } else {
        // zero sentinel rows (row SENT) of both parts of hb0 and hb1
        int u = threadIdx.x;
        if (u < 64) {
            int p = u >> 5;
            hb0[(size_t)p * PPU + (size_t)SENT * 32 + (u & 31)] = 0;
        } else if (u < 128) {
            int v = u - 64;
            int p = v >> 5;
            hb1[(size_t)p * PPU + (size_t)SENT * 32 + (v & 31)] = 0;
        }
    }
}

#define ACC8(A, v) { A[0]+=bf_lo((v).x); A[1]+=bf_hi((v).x); A[2]+=bf_lo((v).y); A[3]+=bf_hi((v).y); \
                     A[4]+=bf_lo((v).z); A[5]+=bf_hi((v).z); A[6]+=bf_lo((v).w); A[7]+=bf_hi((v).w); }

// FUSED csr-build + aggregate + linear, one 32-node tile (== csr bucket).
// CSRB=1 (layer 1): prologue builds localized csr in LDS from part[] and persists
//   lcsr + relative nbeg/nend for layer 2. CSRB=0 (layer 2): stages persisted csr.
// Gather (128B granule): 2 column phases over 2-part-blocked h; per 16-lane group:
//   q=c&7 (uint4 slot of the 128B row-slice), rsl=c>>3 (2 interleaved position
//   chains); 4 rows x 128B in flight per burst; shfl_xor(8) reduce.
// Phase B: 4 waves, wave w owns cols [32w, 32w+32).
template <int RELU, int CSRB>
__global__ __launch_bounds__(256, 7)
void fused_sage(const unsigned* __restrict__ part, const int* __restrict__ bcount,
                int* __restrict__ nbeg, int* __restrict__ nend,
                unsigned short* __restrict__ csr,
                const unsigned* __restrict__ hsrc,
                const unsigned short* __restrict__ WfH,
                const unsigned short* __restrict__ WfL,
                const float* __restrict__ b,
                unsigned short* __restrict__ outb) {
    __shared__ uint4 aggtile[32][16];        // 8KB bf16 agg tile, swizzled slots
    __shared__ unsigned short lcsr[CAP];     // 2KB staged/built csr bucket
    __shared__ int lbe[32][2];               // per-node [beg,end) relative
    __shared__ int ldeg[32];
    __shared__ int lcur[32];
    int tid  = threadIdx.x;
    int lane = tid & 63;
    int g    = tid >> 4;                  // 16-lane group id (0..15)
    int c    = tid & 15;
    int bk   = blockIdx.x;
    int base = bk * CAP;
    int cnt  = bcount[bk];

    if (CSRB) {
        // ---- bucket_csr fused in: hist -> scan -> scatter (LDS-local) ----
        if (tid < 32) ldeg[tid] = 0;
        __syncthreads();
        for (int e = tid; e < cnt; e += 256)
            atomicAdd(&ldeg[part[base + e] >> 16], 1);
        __syncthreads();
        if (tid < 32) {                   // 32-wide scan in wave 0
            int v = ldeg[tid];
            int s = v;
#pragma unroll
            for (int off = 1; off < 32; off <<= 1) {
                int u = __shfl_up(s, off, 32);
                if (tid >= off) s += u;
            }
            int excl = s - v;
            lbe[tid][0] = excl;
            lbe[tid][1] = excl + v;
            lcur[tid]   = excl;
            int node = bk * 32 + tid;
            if (node < N_NODES) { nbeg[node] = excl; nend[node] = excl + v; }
        }
        __syncthreads();
        for (int e = tid; e < cnt; e += 256) {
            unsigned p = part[base + e];
            int pos = atomicAdd(&lcur[p >> 16], 1);
            lcsr[pos] = (unsigned short)(p & 0xFFFFu);
        }
        __syncthreads();
        // persist localized csr for layer 2 (fire-and-forget stores)
        for (int e = tid; e < cnt; e += 256) csr[base + e] = lcsr[e];
    } else {
        for (int e = tid; e < cnt; e += 256) lcsr[e] = csr[base + e];
        if (tid < 32) {
            int node = bk * 32 + tid;
            int b0 = 0, e0 = 0;
            if (node < N_NODES) { b0 = nbeg[node]; e0 = nend[node]; }
            lbe[tid][0] = b0; lbe[tid][1] = e0;
        }
        __syncthreads();
    }

    const uint4* H4 = (const uint4*)hsrc;
    int q   = c & 7;                      // uint4 col-slot within 128B row-slice
    int rsl = c >> 3;                     // position chain 0..1

    // ---- phase A: 2 column phases (no inter-phase sync; slots disjoint) ----
    for (int p = 0; p < 2; ++p) {
        const uint4* Hp = H4 + (size_t)p * PP4;
#pragma unroll
        for (int nn = 0; nn < 2; ++nn) {
            int nl = g + nn * 16;
            int lb = lbe[nl][0], le = lbe[nl][1];
            float a[8] = {0.f,0.f,0.f,0.f,0.f,0.f,0.f,0.f};
            for (int pos = lb + rsl; pos < le; pos += 8) {
                int p1 = pos + 2, p2 = pos + 4, p3 = pos + 6;
                int r0 = (int)lcsr[pos];
                int r1 = (p1 < le) ? (int)lcsr[p1] : SENT;
                int r2 = (p2 < le) ? (int)lcsr[p2] : SENT;
                int r3 = (p3 < le) ? (int)lcsr[p3] : SENT;
                uint4 v0 = Hp[(size_t)r0 * 8 + q];
                uint4 v1 = Hp[(size_t)r1 * 8 + q];
                uint4 v2 = Hp[(size_t)r2 * 8 + q];
                uint4 v3 = Hp[(size_t)r3 * 8 + q];
                ACC8(a, v0); ACC8(a, v1); ACC8(a, v2); ACC8(a, v3);
            }
#pragma unroll
            for (int i = 0; i < 8; ++i)
                a[i] += __shfl_xor(a[i], 8, 64);
            if (rsl == 0) {
                int lb2 = lb, le2 = le;
                float rd = 1.0f / fmaxf((float)(le2 - lb2), 1.0f);
                uint4 o;
                o.x = pack_bf16x2(a[0] * rd, a[1] * rd);
                o.y = pack_bf16x2(a[2] * rd, a[3] * rd);
                o.z = pack_bf16x2(a[4] * rd, a[5] * rd);
                o.w = pack_bf16x2(a[6] * rd, a[7] * rd);
                int s = p * 8 + q;                    // slot s <-> cols 8s..8s+7
                aggtile[nl][s ^ (nl & 7)] = o;
            }
        }
    }
    __syncthreads();

    // ---- phase B: MFMA, wave w owns cols [w*32, w*32+32) ----
    int w    = tid >> 6;                  // col-tile index 0..3
    int ml   = lane & 31;                 // local row 0..31
    int mc   = min(bk * 32 + ml, N_NODES - 1);
    int kh   = lane >> 5;

    floatx16 acc;
#pragma unroll
    for (int i = 0; i < 16; ++i) acc[i] = 0.f;

    // agg term (A from LDS, slot kh+2*ks swizzled by row)
#pragma unroll
    for (int ks = 0; ks < 8; ++ks) {
        int slot = (kh + 2 * ks) ^ (ml & 7);
        short8 aa = *(const short8*)&aggtile[ml][slot];
        int cbase = (ks * 4 + w) * 64 + lane;
        short8 bh = *(const short8*)(WfH + (size_t)cbase * 8);
        short8 bl = *(const short8*)(WfL + (size_t)cbase * 8);
        acc = __builtin_amdgcn_mfma_f32_32x32x16_bf16(aa, bh, acc, 0, 0, 0);
        acc = __builtin_amdgcn_mfma_f32_32x32x16_bf16(aa, bl, acc, 0, 0, 0);
    }
    // self term (A from 2-part-blocked global h rows)
#pragma unroll
    for (int ks = 0; ks < 8; ++ks) {
        int c8 = ks * 2 + kh;             // uint4 col-slot 0..15
        short8 aa = *(const short8*)&H4[(size_t)(c8 >> 3) * PP4 + (size_t)mc * 8 + (c8 & 7)];
        int cbase = ((8 + ks) * 4 + w) * 64 + lane;
        short8 bh = *(const short8*)(WfH + (size_t)cbase * 8);
        short8 bl = *(const short8*)(WfL + (size_t)cbase * 8);
        acc = __builtin_amdgcn_mfma_f32_32x32x16_bf16(aa, bh, acc, 0, 0, 0);
        acc = __builtin_amdgcn_mfma_f32_32x32x16_bf16(aa, bl, acc, 0, 0, 0);
    }

    int col0 = w * 32 + (lane & 31);
    float bb = b[col0];
    unsigned short* outp = outb + (size_t)(w >> 1) * (PPU * 2);   // part, ushort units
#pragma unroll
    for (int reg = 0; reg < 16; ++reg) {
        int rloc = (reg & 3) + 8 * (reg >> 2) + 4 * kh;   // C/D row map (m74/m101)
        int rowg = bk * 32 + rloc;
        if (rowg < N_NODES) {
            float v0 = acc[reg] + bb;
            if (RELU) v0 = fmaxf(v0, 0.f);
            outp[(size_t)rowg * 64 + (col0 & 63)] = f32_to_bf16(v0);
        }
    }
}

// logits from 2-part-blocked bf16 h2; 8 lanes/edge, TWO edges per lane:
// per endpoint, 4 lanes coalesce on one 128B line; 8 loads in flight per lane.
__global__ void edge_dot(const int* __restrict__ esrc, const int* __restrict__ edst,
                         const unsigned* __restrict__ h2b, float* __restrict__ out) {
    int t = blockIdx.x * blockDim.x + threadIdx.x;
    int e0 = t >> 3, c = t & 7;
    const int HALF = N_LABEL / 2;
    if (e0 >= HALF) return;
    int e1 = e0 + HALF;
    const uint4* H = (const uint4*)h2b;
    int p  = c >> 2;                       // part 0..1
    int s0 = (c & 3) * 2, s1 = s0 + 1;     // uint4 slots within 128B part row
    size_t pb = (size_t)p * PP4;
    int rs0 = esrc[e0], rd0 = edst[e0];
    int rs1 = esrc[e1], rd1 = edst[e1];
    uint4 a0 = H[pb + (size_t)rs0 * 8 + s0];
    uint4 a1 = H[pb + (size_t)rs0 * 8 + s1];
    uint4 b0 = H[pb + (size_t)rd0 * 8 + s0];
    uint4 b1 = H[pb + (size_t)rd0 * 8 + s1];
    uint4 a2 = H[pb + (size_t)rs1 * 8 + s0];
    uint4 a3 = H[pb + (size_t)rs1 * 8 + s1];
    uint4 b2 = H[pb + (size_t)rd1 * 8 + s0];
    uint4 b3 = H[pb + (size_t)rd1 * 8 + s1];
    float p0 = bf_lo(a0.x) * bf_lo(b0.x) + bf_hi(a0.x) * bf_hi(b0.x)
             + bf_lo(a0.y) * bf_lo(b0.y) + bf_hi(a0.y) * bf_hi(b0.y)
             + bf_lo(a0.z) * bf_lo(b0.z) + bf_hi(a0.z) * bf_hi(b0.z)
             + bf_lo(a0.w) * bf_lo(b0.w) + bf_hi(a0.w) * bf_hi(b0.w)
             + bf_lo(a1.x) * bf_lo(b1.x) + bf_hi(a1.x) * bf_hi(b1.x)
             + bf_lo(a1.y) * bf_lo(b1.y) + bf_hi(a1.y) * bf_hi(b1.y)
             + bf_lo(a1.z) * bf_lo(b1.z) + bf_hi(a1.z) * bf_hi(b1.z)
             + bf_lo(a1.w) * bf_lo(b1.w) + bf_hi(a1.w) * bf_hi(b1.w);
    float p1 = bf_lo(a2.x) * bf_lo(b2.x) + bf_hi(a2.x) * bf_hi(b2.x)
             + bf_lo(a2.y) * bf_lo(b2.y) + bf_hi(a2.y) * bf_hi(b2.y)
             + bf_lo(a2.z) * bf_lo(b2.z) + bf_hi(a2.z) * bf_hi(b2.z)
             + bf_lo(a2.w) * bf_lo(b2.w) + bf_hi(a2.w) * bf_hi(b2.w)
             + bf_lo(a3.x) * bf_lo(b3.x) + bf_hi(a3.x) * bf_hi(b3.x)
             + bf_lo(a3.y) * bf_lo(b3.y) + bf_hi(a3.y) * bf_hi(b3.y)
             + bf_lo(a3.z) * bf_lo(b3.z) + bf_hi(a3.z) * bf_hi(b3.z)
             + bf_lo(a3.w) * bf_lo(b3.w) + bf_hi(a3.w) * bf_hi(b3.w);
#pragma unroll
    for (int off = 4; off; off >>= 1) {
        p0 += __shfl_down(p0, off, 8);
        p1 += __shfl_down(p1, off, 8);
    }
    if (c == 0) { out[e0] = p0; out[e1] = p1; }
}

extern "C" void kernel_launch(void* const* d_in, const int* in_sizes, int n_in,
                              void* d_out, int out_size, void* d_ws, size_t ws_size,
                              hipStream_t stream) {
    const int*   n_id     = (const int*)d_in[0];
    const float* x_struct = (const float*)d_in[1];
    const int*   e_idx    = (const int*)d_in[2];   // [2, N_EDGES]
    const int*   eli      = (const int*)d_in[3];   // [2, N_LABEL]
    const float* emb      = (const float*)d_in[4];
    const float* W1l      = (const float*)d_in[5];
    const float* W1r      = (const float*)d_in[6];
    const float* b1       = (const float*)d_in[7];
    const float* W2l      = (const float*)d_in[8];
    const float* W2r      = (const float*)d_in[9];
    const float* b2       = (const float*)d_in[10];
    float* out = (float*)d_out;

    const int* src = e_idx;
    const int* dst = e_idx + N_EDGES;

    const size_t ROWS = (size_t)2 * PPU;           // uints per table (2 parts)
    unsigned* hb2 = (unsigned*)d_ws;               // bf16 h2 (edge_dot input)
    unsigned* hb0 = hb2 + ROWS;                    // bf16 h0 (+sentinel)
    unsigned* hb1 = hb0 + ROWS;                    // bf16 h1 (+sentinel)
    int*   nbeg   = (int*)(hb1 + ROWS);            // relative [beg,end) per node
    int*   nend   = nbeg + N_NODES;
    int*   bcount = nend + N_NODES;                // NBUCK
    unsigned* part= (unsigned*)(bcount + NBUCK);   // NBUCK*CAP packed (src | local<<16)
    unsigned short* csr = (unsigned short*)(part + (size_t)NBUCK * CAP);  // NBUCK*CAP ushort
    uintptr_t wa  = ((uintptr_t)(csr + (size_t)NBUCK * CAP) + 15) & ~(uintptr_t)15;
    unsigned short* WfH = (unsigned short*)wa;     // 2*32768
    unsigned short* WfL = WfH + 2 * 32768;

    // bcount <- 0 (capture-safe async memset; 6KB)
    hipMemsetAsync(bcount, 0, NBUCK * sizeof(int), stream);

    // merged front-end: part_scatter (blocks 0..249, overlapped) + hb0 build +
    // W swizzle + sentinel zero
    build_all<<<NPBLK + 6283, 256, 0, stream>>>(
        n_id, emb, x_struct, hb0, hb1, src, dst, bcount, part,
        W1l, W1r, W2l, W2r, WfH, WfL);

    // layer 1: fused csr-build + aggregate + linear -> bf16 h1 (persists csr)
    fused_sage<1, 1><<<NBUCK, 256, 0, stream>>>(
        part, bcount, nbeg, nend, csr, hb0, WfH, WfL, b1, (unsigned short*)hb1);

    // layer 2: fused aggregate + linear -> bf16 h2
    fused_sage<0, 0><<<NBUCK, 256, 0, stream>>>(
        part, bcount, nbeg, nend, csr, hb1, WfH + 32768, WfL + 32768, b2,
        (unsigned short*)hb2);

    edge_dot<<<(N_LABEL / 2 * 8 + 255) / 256, 256, 0, stream>>>(eli, eli + N_LABEL, hb2, out);
}